// Round 1
// baseline (228.146 us; speedup 1.0000x reference)
//
#include <hip/hip_runtime.h>

// ---------------- problem constants ----------------
#define N1 27648            // 96*96*3
#define N2 6912             // 48*48*3
#define N3 1728             // 24*24*3
#define NTOT 36288          // N1+N2+N3
#define BATCH_ 16
#define C_ 3
#define MROWS (NTOT * C_)   // 108864
#define TOPK 500
#define NBINS 9216          // (0x3F800000 - 0x3D400000) >> 12
#define CCAP 2048
#define BASEBITS 0x3D400000u

__device__ __forceinline__ float sigm(float x) { return 1.0f / (1.0f + expf(-x)); }

// score for candidate (b, n, c); identical op sequence everywhere
__device__ __forceinline__ float score_of(int b, int n, int c,
    const float* __restrict__ o1, const float* __restrict__ o2, const float* __restrict__ o3)
{
    const float* o; int ln, Ns;
    if (n < N1)           { o = o1; ln = n;             Ns = N1; }
    else if (n < N1 + N2) { o = o2; ln = n - N1;        Ns = N2; }
    else                  { o = o3; ln = n - (N1 + N2); Ns = N3; }
    const float* r = o + ((size_t)b * Ns + ln) * 8;
    return sigm(r[4]) * sigm(r[5 + c]);
}

// decoded corner box for anchor (b, n); identical op sequence in both kernels
__device__ __forceinline__ void box_of(int b, int n,
    const float* __restrict__ o1, const float* __restrict__ o2, const float* __restrict__ o3,
    const float* __restrict__ a1, const float* __restrict__ a2, const float* __restrict__ a3,
    const float* __restrict__ f1, const float* __restrict__ f2, const float* __restrict__ f3,
    const float* __restrict__ s1, const float* __restrict__ s2, const float* __restrict__ s3,
    float bx[4])
{
    const float *o, *anc, *off, *st; int ln, Ns;
    if (n < N1)           { o = o1; anc = a1; off = f1; st = s1; ln = n;             Ns = N1; }
    else if (n < N1 + N2) { o = o2; anc = a2; off = f2; st = s2; ln = n - N1;        Ns = N2; }
    else                  { o = o3; anc = a3; off = f3; st = s3; ln = n - (N1 + N2); Ns = N3; }
    const float* r = o + ((size_t)b * Ns + ln) * 8;
    float sx = sigm(r[0]);
    float sy = sigm(r[1]);
    float cx = (sx + off[2 * ln + 0]) * st[0];
    float cy = (sy + off[2 * ln + 1]) * st[1];
    float hx = 0.5f * expf(r[2]) * anc[2 * ln + 0];
    float hy = 0.5f * expf(r[3]) * anc[2 * ln + 1];
    bx[0] = cx - hx; bx[1] = cy - hy; bx[2] = cx + hx; bx[3] = cy + hy;
}

// ---------------- kernel 1: decode (defaults + bboxes) ----------------
__global__ __launch_bounds__(256) void decode_kernel(
    const float* __restrict__ o1, const float* __restrict__ o2, const float* __restrict__ o3,
    const float* __restrict__ a1, const float* __restrict__ a2, const float* __restrict__ a3,
    const float* __restrict__ f1, const float* __restrict__ f2, const float* __restrict__ f3,
    const float* __restrict__ s1, const float* __restrict__ s2, const float* __restrict__ s3,
    float* __restrict__ out)
{
    int g = blockIdx.x * 256 + threadIdx.x;
    if (g >= BATCH_ * NTOT) return;
    int b = g / NTOT;
    int n = g - b * NTOT;

    float bx[4];
    box_of(b, n, o1, o2, o3, a1, a2, a3, f1, f2, f3, s1, s2, s3, bx);

    size_t base = (size_t)b * MROWS + (size_t)n * C_;
    float* ids = out;
    float* scs = out + (size_t)BATCH_ * MROWS;
    float* bbs = out + 2ull * BATCH_ * MROWS;

    ids[base + 0] = -1.0f; ids[base + 1] = -1.0f; ids[base + 2] = -1.0f;
    scs[base + 0] = -1.0f; scs[base + 1] = -1.0f; scs[base + 2] = -1.0f;

    float4 v = make_float4(bx[0], bx[1], bx[2], bx[3]);
    float4* bp = (float4*)(bbs + base * 4);
    bp[0] = v; bp[1] = v; bp[2] = v;
}

// ---------------- kernel 2: per-(b,c) top-500 selection + greedy NMS ----------------
__global__ __launch_bounds__(1024) void select_nms_kernel(
    const float* __restrict__ o1, const float* __restrict__ o2, const float* __restrict__ o3,
    const float* __restrict__ a1, const float* __restrict__ a2, const float* __restrict__ a3,
    const float* __restrict__ f1, const float* __restrict__ f2, const float* __restrict__ f3,
    const float* __restrict__ s1, const float* __restrict__ s2, const float* __restrict__ s3,
    float* __restrict__ out)
{
    const int b = blockIdx.x / C_;
    const int c = blockIdx.x - b * C_;
    const int tid = threadIdx.x;

    // 7048 * 8B = 56384 B; hist (36864 B) aliases keys/boxes/part-of-masks (phase-separated)
    __shared__ unsigned long long smem[7048];
    __shared__ unsigned int chunkSum[1024];
    __shared__ unsigned int sh_tb, sh_cnt;
    __shared__ unsigned long long keepw[8];

    unsigned int* hist = (unsigned int*)smem;                    // [9216]
    unsigned long long* keys = smem;                             // [2048]
    float* boxes = (float*)(smem + CCAP);                        // [500*4]
    unsigned long long* masks = smem + CCAP + 1000;              // [500*8]

    // ---- phase 1: histogram of score bit-patterns ----
    for (int i = tid; i < NBINS; i += 1024) hist[i] = 0u;
    __syncthreads();

    for (int n = tid; n < NTOT; n += 1024) {
        float s = score_of(b, n, c, o1, o2, o3);
        if (s > 0.05f) {
            unsigned bin = (__float_as_uint(s) - BASEBITS) >> 12;
            if (bin > NBINS - 1u) bin = NBINS - 1u;
            atomicAdd(&hist[bin], 1u);
        }
    }
    __syncthreads();

    // ---- phase 2: suffix scan -> threshold bin containing the 500th score ----
    {
        unsigned sum = 0;
        int hb = tid * 9;
        #pragma unroll
        for (int k = 0; k < 9; ++k) sum += hist[hb + k];
        chunkSum[tid] = sum;
        __syncthreads();
        for (int off = 1; off < 1024; off <<= 1) {
            unsigned v = (tid + off < 1024) ? chunkSum[tid + off] : 0u;
            __syncthreads();
            chunkSum[tid] += v;
            __syncthreads();
        }
        unsigned sfx  = chunkSum[tid];
        unsigned sfxn = (tid < 1023) ? chunkSum[tid + 1] : 0u;
        if (tid == 0 && sfx < TOPK) sh_tb = 0u;     // fewer than 500 candidates total
        if (sfx >= TOPK && sfxn < TOPK) {           // unique crossing chunk
            unsigned cum = sfxn;
            unsigned tb = (unsigned)hb;
            for (int k = 8; k >= 0; --k) {
                cum += hist[hb + k];
                if (cum >= TOPK) { tb = (unsigned)(hb + k); break; }
            }
            sh_tb = tb;
        }
        if (tid == 0) sh_cnt = 0u;
    }
    __syncthreads();

    // ---- phase 3: collect all candidates in bins >= tb ----
    const unsigned tb = sh_tb;
    for (int n = tid; n < NTOT; n += 1024) {
        float s = score_of(b, n, c, o1, o2, o3);
        if (s > 0.05f) {
            unsigned bits = __float_as_uint(s);
            unsigned bin = (bits - BASEBITS) >> 12;
            if (bin > NBINS - 1u) bin = NBINS - 1u;
            if (bin >= tb) {
                unsigned p = atomicAdd(&sh_cnt, 1u);
                if (p < CCAP)
                    keys[p] = ((unsigned long long)bits << 32) | (unsigned)(~n);
            }
        }
    }
    __syncthreads();

    const unsigned cnt = min(sh_cnt, (unsigned)CCAP);
    for (int i = tid; i < CCAP; i += 1024)
        if (i >= (int)cnt) keys[i] = 0ull;
    __syncthreads();

    // ---- phase 4: bitonic sort, descending (score desc, index asc) ----
    for (unsigned k = 2; k <= (unsigned)CCAP; k <<= 1) {
        for (unsigned j = k >> 1; j > 0; j >>= 1) {
            for (unsigned i = tid; i < (unsigned)CCAP; i += 1024) {
                unsigned ixj = i ^ j;
                if (ixj > i) {
                    unsigned long long x = keys[i], y = keys[ixj];
                    bool desc = ((i & k) == 0);
                    if (desc ? (x < y) : (x > y)) { keys[i] = y; keys[ixj] = x; }
                }
            }
            __syncthreads();
        }
    }

    const int K = (int)min(cnt, (unsigned)TOPK);

    // ---- phase 5: decode boxes of top-K ----
    if (tid < K) {
        unsigned idx = ~(unsigned)(keys[tid] & 0xFFFFFFFFull);
        float bx[4];
        box_of(b, (int)idx, o1, o2, o3, a1, a2, a3, f1, f2, f3, s1, s2, s3, bx);
        boxes[tid * 4 + 0] = bx[0]; boxes[tid * 4 + 1] = bx[1];
        boxes[tid * 4 + 2] = bx[2]; boxes[tid * 4 + 3] = bx[3];
    }
    __syncthreads();

    // ---- phase 6: overlap bitmasks (thread i covers j > i) ----
    if (tid < K) {
        const int i = tid;
        float xi1 = boxes[i*4+0], yi1 = boxes[i*4+1], xi2 = boxes[i*4+2], yi2 = boxes[i*4+3];
        float ai = fmaxf(xi2 - xi1, 0.0f) * fmaxf(yi2 - yi1, 0.0f);
        #pragma unroll 1
        for (int w = 0; w < 8; ++w) {
            unsigned long long word = 0ull;
            int jlo = (i + 1 > w * 64) ? i + 1 : w * 64;
            int jhi = (K < (w + 1) * 64) ? K : (w + 1) * 64;
            for (int j = jlo; j < jhi; ++j) {
                float xj1 = boxes[j*4+0], yj1 = boxes[j*4+1], xj2 = boxes[j*4+2], yj2 = boxes[j*4+3];
                float aj = fmaxf(xj2 - xj1, 0.0f) * fmaxf(yj2 - yj1, 0.0f);
                float iw = fmaxf(fminf(xi2, xj2) - fmaxf(xi1, xj1), 0.0f);
                float ih = fmaxf(fminf(yi2, yj2) - fmaxf(yi1, yj1), 0.0f);
                float inter = iw * ih;
                float iou = inter / (ai + aj - inter + 1e-12f);
                if (iou > 0.5f) word |= 1ull << (j & 63);
            }
            masks[i * 8 + w] = word;
        }
    }
    __syncthreads();

    // ---- phase 7: greedy scan (wave 0; lane w owns bitset word w) ----
    if (tid < 64) {
        unsigned long long removed = 0ull, keep = 0ull;
        for (int i = 0; i < K; ++i) {
            int w = i >> 6, bp = i & 63;
            unsigned long long rw = __shfl(removed, w);
            if (!((rw >> bp) & 1ull)) {
                if (tid == w) keep |= 1ull << bp;
                if (tid < 8) removed |= masks[i * 8 + tid];
            }
        }
        if (tid < 8) keepw[tid] = keep;
    }
    __syncthreads();

    // ---- phase 8: scatter kept entries into output ----
    if (tid < K) {
        if ((keepw[tid >> 6] >> (tid & 63)) & 1ull) {
            unsigned long long key = keys[tid];
            unsigned idx = ~(unsigned)(key & 0xFFFFFFFFull);
            float sc = __uint_as_float((unsigned)(key >> 32));
            size_t row = (size_t)b * MROWS + (size_t)idx * C_ + c;
            out[row] = (float)c;                               // id
            out[(size_t)BATCH_ * MROWS + row] = sc;            // score
        }
    }
}

extern "C" void kernel_launch(void* const* d_in, const int* in_sizes, int n_in,
                              void* d_out, int out_size, void* d_ws, size_t ws_size,
                              hipStream_t stream)
{
    const float* o1 = (const float*)d_in[0];
    const float* o2 = (const float*)d_in[1];
    const float* o3 = (const float*)d_in[2];
    const float* a1 = (const float*)d_in[3];
    const float* a2 = (const float*)d_in[4];
    const float* a3 = (const float*)d_in[5];
    const float* f1 = (const float*)d_in[6];
    const float* f2 = (const float*)d_in[7];
    const float* f3 = (const float*)d_in[8];
    const float* s1 = (const float*)d_in[9];
    const float* s2 = (const float*)d_in[10];
    const float* s3 = (const float*)d_in[11];
    float* out = (float*)d_out;

    int total = BATCH_ * NTOT;
    decode_kernel<<<dim3((total + 255) / 256), dim3(256), 0, stream>>>(
        o1, o2, o3, a1, a2, a3, f1, f2, f3, s1, s2, s3, out);
    select_nms_kernel<<<dim3(BATCH_ * C_), dim3(1024), 0, stream>>>(
        o1, o2, o3, a1, a2, a3, f1, f2, f3, s1, s2, s3, out);
}